// Round 8
// baseline (447.255 us; speedup 1.0000x reference)
//
#include <hip/hip_runtime.h>
#include <stdint.h>

// Problem constants
#define T_TOK 4096
#define H_DIM 4096
#define I_DIM 1408
#define E_NUM 16
#define TPE   256

typedef __attribute__((ext_vector_type(4))) int   i32x4;
typedef __attribute__((ext_vector_type(4))) float f32x4;

// counted waits / barriers (T4): never drain vmcnt to 0 in the main loop.
#define VMCNT(n) asm volatile("s_waitcnt vmcnt(" #n ")" ::: "memory")
#define LGKM0()  asm volatile("s_waitcnt lgkmcnt(0)" ::: "memory")
#define BARRIER() asm volatile("s_barrier" ::: "memory")
#define FENCE()  asm volatile("" ::: "memory")   // pin VMEM issue order

// async global->LDS, 16B/lane. LDS dest is WAVE-UNIFORM base; HW writes
// base + lane*16. Global src is per-lane (so we pre-swizzle the source).
__device__ __forceinline__ void gload16(const void* g, void* l) {
  __builtin_amdgcn_global_load_lds(
      (const __attribute__((address_space(1))) void*)g,
      (__attribute__((address_space(3))) void*)l, 16, 0, 0);
}

// swizzle key: involution on the 4 16B-blocks of a 64B LDS row.
__device__ __forceinline__ int fswz(int r) { return (r ^ (r >> 2)) & 3; }

// ---------------------------------------------------------------------------
// Kernel 1: dynamic per-token quant of x (f32 -> int8 + scale). 1 block/token.
// ---------------------------------------------------------------------------
__global__ __launch_bounds__(256)
void quant_x_kernel(const float* __restrict__ x,
                    int8_t* __restrict__ xq,
                    float* __restrict__ s1) {
  const int t   = blockIdx.x;
  const int tid = threadIdx.x;
  const float* row = x + (size_t)t * H_DIM;

  f32x4 v[4];
  float mx = 0.0f;
#pragma unroll
  for (int i = 0; i < 4; ++i) {
    v[i] = *(const f32x4*)(row + (size_t)(i * 256 + tid) * 4);
#pragma unroll
    for (int j = 0; j < 4; ++j) mx = fmaxf(mx, fabsf(v[i][j]));
  }
#pragma unroll
  for (int off = 32; off > 0; off >>= 1) mx = fmaxf(mx, __shfl_xor(mx, off));
  __shared__ float wmax[4];
  if ((tid & 63) == 0) wmax[tid >> 6] = mx;
  __syncthreads();
  float s = fmaxf(fmaxf(wmax[0], wmax[1]), fmaxf(wmax[2], wmax[3])) / 127.0f;
  s = fmaxf(s, 1e-30f);

  int* orow = (int*)(xq + (size_t)t * H_DIM);
#pragma unroll
  for (int i = 0; i < 4; ++i) {
    int packed = 0;
#pragma unroll
    for (int j = 0; j < 4; ++j) {
      float q = rintf(v[i][j] / s);              // rintf = half-even = jnp.round
      q = fminf(fmaxf(q, -128.0f), 127.0f);
      packed |= ((int)q & 0xff) << (8 * j);
    }
    orow[i * 256 + tid] = packed;
  }
  if (tid == 0) s1[t] = s;
}

// ---------------------------------------------------------------------------
// Kernel 3: h = silu(gate)*up*smooth; per-token quant -> hq, s2. 1 block/token.
// ---------------------------------------------------------------------------
__global__ __launch_bounds__(256)
void act_quant_kernel(const float* __restrict__ y,
                      const float* __restrict__ smooth,
                      int8_t* __restrict__ hq,
                      float* __restrict__ s2) {
  const int t   = blockIdx.x;
  const int e   = t >> 8;               // TPE = 256
  const int tid = threadIdx.x;
  const float* gate = y + (size_t)t * (2 * I_DIM);
  const float* up   = gate + I_DIM;
  const float* ss   = smooth + (size_t)e * I_DIM;
  constexpr int NV = I_DIM / 4;          // 352 vec4 per row

  f32x4 h[2];
  float mx = 0.0f;
#pragma unroll
  for (int i = 0; i < 2; ++i) {
    const int idx = tid + i * 256;
    h[i] = (f32x4)(0.0f);
    if (idx < NV) {
      const f32x4 g4 = *(const f32x4*)(gate + idx * 4);
      const f32x4 u4 = *(const f32x4*)(up + idx * 4);
      const f32x4 s4 = *(const f32x4*)(ss + idx * 4);
#pragma unroll
      for (int j = 0; j < 4; ++j) {
        const float g = g4[j];
        const float sig = 1.0f / (1.0f + expf(-g));
        h[i][j] = ((g * sig) * u4[j]) * s4[j];
        mx = fmaxf(mx, fabsf(h[i][j]));
      }
    }
  }
#pragma unroll
  for (int off = 32; off > 0; off >>= 1) mx = fmaxf(mx, __shfl_xor(mx, off));
  __shared__ float wmax[4];
  if ((tid & 63) == 0) wmax[tid >> 6] = mx;
  __syncthreads();
  float s = fmaxf(fmaxf(wmax[0], wmax[1]), fmaxf(wmax[2], wmax[3])) / 127.0f;
  s = fmaxf(s, 1e-30f);

  int* orow = (int*)(hq + (size_t)t * I_DIM);   // 1408 % 16 == 0, aligned
#pragma unroll
  for (int i = 0; i < 2; ++i) {
    const int idx = tid + i * 256;
    if (idx < NV) {
      int packed = 0;
#pragma unroll
      for (int j = 0; j < 4; ++j) {
        float q = rintf(h[i][j] / s);
        q = fminf(fmaxf(q, -128.0f), 127.0f);
        packed |= ((int)q & 0xff) << (8 * j);
      }
      orow[idx] = packed;
    }
  }
  if (tid == 0) s2[t] = s;
}

// ---------------------------------------------------------------------------
// Grouped int8 GEMM, weights arrive as INT32 (truncated to int8 on the fly).
//   A: (E*TPE, K) int8; B32: (E, N, K) int32; C = ((f32)acc*sN[e,n])*sM[t]
// Tile M=256 (whole expert: weight bytes read ONCE) x N=64, BK=64.
// 512 thr = 8 waves (4M x 2N); wave = 64x32 = 4x2 mfma_i32_16x16x64_i8 frags.
//
// Counted-vmcnt pipeline (one raw s_barrier/iter, NO vmcnt(0) in steady loop):
//   As ring of 4 (A prefetch 2 tiles ahead, global_load_lds w16)
//   Bs ring of 2 (B int32 quad -> regs at iter t, packed+ds_written for t+1)
// Per-iter VMEM issue order (pinned by FENCE): [B(t+1) x4][A(t+2) x2].
// Wait math (per wave, oldest-drains-first):
//   doB c-wait  vmcnt(8): drains A(t)   (outstanding <= A(t+1)2 B(t+1)4 A(t+2)2)
//   doB d-wait  vmcnt(2): drains B(t+1) (leaves A(t+2)2 in flight)
//   non-doB c-wait vmcnt(4): drains A(t) (outstanding <= A(t)2 A(t+1)2 A(t+2)2)
// Tails fall back to tighter literals (see branches).
// XCD-pinned mapping: rid&7 = XCD, each XCD owns 2 whole experts -> expert's
// A tile (1MB/0.35MB) stays resident in that XCD's 4MB L2.
// ---------------------------------------------------------------------------
template <int N, int K, int NBLK>   // NBLK = N/64
__global__ __launch_bounds__(512, 4)
void gemm_i8_w32_kernel(const int8_t* __restrict__ A,
                        const int* __restrict__ B32,
                        float* __restrict__ C,
                        const float* __restrict__ scaleN,
                        const float* __restrict__ scaleM) {
  constexpr int NT = K / 64;
  __shared__ __align__(16) int8_t As[4][256 * 64];   // 16 KB each (64 KB)
  __shared__ __align__(16) int8_t Bs[2][64 * 64];    //  4 KB each (8 KB)

  const int rid  = blockIdx.x;
  const int xcd  = rid & 7;
  const int slot = rid >> 3;                 // 0 .. 2*NBLK-1
  const int el   = (slot >= NBLK) ? 1 : 0;
  const int e    = 2 * xcd + el;
  const int bn   = slot - el * NBLK;

  const int tid  = threadIdx.x;
  const int lane = tid & 63;
  const int wid  = tid >> 6;          // 0..7
  const int wm   = wid >> 1;          // 0..3  (64-row quadrant of 256)
  const int wn   = wid & 1;           // 0..1  (32-col half of 64)
  const bool doB = (tid < 256);

  const int8_t* Abase = A + (size_t)e * TPE * K;
  const int*    Bbase = B32 + ((size_t)e * N + (size_t)bn * 64) * (size_t)K;

  // --- A staging addresses (2 chunks of 128 rows; 16B per lane) ---
  const int arow0 = wid * 16 + (lane >> 2);           // 0..127
  const int ablk  = lane & 3;
  const int8_t* gA0 = Abase + (size_t)arow0 * K + ((ablk ^ fswz(arow0)) << 4);
  const int arow1 = 128 + arow0;
  const int8_t* gA1 = Abase + (size_t)arow1 * K + ((ablk ^ fswz(arow1)) << 4);

  // --- B staging (waves 0-3): one 64B chunk per thread (64 rows x 4 blks) ---
  const int brow = (tid & 255) >> 2;                  // 0..63
  const int bblk = tid & 3;
  const int* gB = Bbase + (size_t)brow * K + (bblk << 4);   // int units
  const int bldsOff = brow * 64 + ((bblk ^ fswz(brow)) << 4);

  // --- MFMA fragment LDS read offsets (same XOR on read) ---
  const int r15 = lane & 15;
  const int kg  = lane >> 4;
  int aoff[4], boff[2];
#pragma unroll
  for (int m = 0; m < 4; ++m) {
    const int r = wm * 64 + m * 16 + r15;             // 0..255
    aoff[m] = r * 64 + ((kg ^ fswz(r)) << 4);
  }
#pragma unroll
  for (int n = 0; n < 2; ++n) {
    const int r = wn * 32 + n * 16 + r15;             // 0..63
    boff[n] = r * 64 + ((kg ^ fswz(r)) << 4);
  }

  i32x4 acc[4][2] = {};

  // ---- prologue: issue [B(0)][A(0)][A(1)]; wait B(0) only; write Bs[0] ----
  if (doB) {
    i32x4 b0 = __builtin_nontemporal_load((const i32x4*)(gB + 0));
    i32x4 b1 = __builtin_nontemporal_load((const i32x4*)(gB + 4));
    i32x4 b2 = __builtin_nontemporal_load((const i32x4*)(gB + 8));
    i32x4 b3 = __builtin_nontemporal_load((const i32x4*)(gB + 12));
    FENCE();
    gload16(gA0, &As[0][wid * 1024]);
    gload16(gA1, &As[0][8192 + wid * 1024]);
    gload16(gA0 + 64, &As[1][wid * 1024]);
    gload16(gA1 + 64, &As[1][8192 + wid * 1024]);
    VMCNT(4);                       // B(0) done; A(0),A(1) still in flight
    i32x4 pk;
    pk[0] = (b0[0] & 255) | ((b0[1] & 255) << 8) | ((b0[2] & 255) << 16) | (b0[3] << 24);
    pk[1] = (b1[0] & 255) | ((b1[1] & 255) << 8) | ((b1[2] & 255) << 16) | (b1[3] << 24);
    pk[2] = (b2[0] & 255) | ((b2[1] & 255) << 8) | ((b2[2] & 255) << 16) | (b2[3] << 24);
    pk[3] = (b3[0] & 255) | ((b3[1] & 255) << 8) | ((b3[2] & 255) << 16) | (b3[3] << 24);
    *(i32x4*)(&Bs[0][bldsOff]) = pk;
    LGKM0();
  } else {
    FENCE();
    gload16(gA0, &As[0][wid * 1024]);
    gload16(gA1, &As[0][8192 + wid * 1024]);
    gload16(gA0 + 64, &As[1][wid * 1024]);
    gload16(gA1 + 64, &As[1][8192 + wid * 1024]);
  }

  for (int t = 0; t < NT; ++t) {
    const int buf4 = t & 3;
    const int buf2 = t & 1;
    const bool moreB = (t + 1) < NT;
    const bool moreA = (t + 2) < NT;

    // (a) next B tile -> regs (nt: stream-once weights, keep L2 for A)
    i32x4 n0, n1, n2, n3;
    if (doB && moreB) {
      const int* g = gB + (t + 1) * 64;
      n0 = __builtin_nontemporal_load((const i32x4*)(g + 0));
      n1 = __builtin_nontemporal_load((const i32x4*)(g + 4));
      n2 = __builtin_nontemporal_load((const i32x4*)(g + 8));
      n3 = __builtin_nontemporal_load((const i32x4*)(g + 12));
    }
    FENCE();
    // (b) A tile t+2 -> As ring
    if (moreA) {
      const size_t ko = (size_t)(t + 2) * 64;
      const int rb = (t + 2) & 3;
      gload16(gA0 + ko, &As[rb][wid * 1024]);
      gload16(gA1 + ko, &As[rb][8192 + wid * 1024]);
    }
    // (c) counted wait: A(t) complete for THIS wave, then barrier for all
    if (doB) {
      VMCNT(8);                     // chain-correct incl. tails (see header)
    } else {
      if (t < NT - 2)      VMCNT(4);
      else if (t == NT - 2) VMCNT(2);
      else                  VMCNT(0);
    }
    BARRIER();
    // compute tile t
    i32x4 av[4], bv[2];
#pragma unroll
    for (int m = 0; m < 4; ++m) av[m] = *(const i32x4*)(&As[buf4][aoff[m]]);
#pragma unroll
    for (int n = 0; n < 2; ++n) bv[n] = *(const i32x4*)(&Bs[buf2][boff[n]]);
#pragma unroll
    for (int m = 0; m < 4; ++m)
#pragma unroll
      for (int n = 0; n < 2; ++n)
        acc[m][n] = __builtin_amdgcn_mfma_i32_16x16x64_i8(av[m], bv[n], acc[m][n], 0, 0, 0);
    // (d) wait B(t+1) regs, pack, swizzled write into Bs[t+1 & 1]
    if (doB && moreB) {
      if (moreA) VMCNT(2); else VMCNT(0);
      i32x4 pk;
      pk[0] = (n0[0] & 255) | ((n0[1] & 255) << 8) | ((n0[2] & 255) << 16) | (n0[3] << 24);
      pk[1] = (n1[0] & 255) | ((n1[1] & 255) << 8) | ((n1[2] & 255) << 16) | (n1[3] << 24);
      pk[2] = (n2[0] & 255) | ((n2[1] & 255) << 8) | ((n2[2] & 255) << 16) | (n2[3] << 24);
      pk[3] = (n3[0] & 255) | ((n3[1] & 255) << 8) | ((n3[2] & 255) << 16) | (n3[3] << 24);
      *(i32x4*)(&Bs[buf2 ^ 1][bldsOff]) = pk;
      LGKM0();                      // ds_write visible before next barrier
    }
  }

  // --- epilogue: C/D layout col = lane&15, row = (lane>>4)*4 + reg ---
  const float* sN = scaleN + (size_t)e * N + (size_t)bn * 64;
  const float* sM = scaleM + e * TPE;
  float* Cbase = C + (size_t)e * TPE * N + (size_t)bn * 64;
#pragma unroll
  for (int m = 0; m < 4; ++m) {
#pragma unroll
    for (int j = 0; j < 4; ++j) {
      const int row = wm * 64 + m * 16 + kg * 4 + j;   // token row 0..255
      const float smv = sM[row];
      float* cr = Cbase + (size_t)row * N;
#pragma unroll
      for (int n = 0; n < 2; ++n) {
        const int col = wn * 32 + n * 16 + r15;
        cr[col] = ((float)acc[m][n][j] * sN[col]) * smv;  // ref mult order
      }
    }
  }
}

// ---------------------------------------------------------------------------
extern "C" void kernel_launch(void* const* d_in, const int* in_sizes, int n_in,
                              void* d_out, int out_size, void* d_ws, size_t ws_size,
                              hipStream_t stream) {
  const float* x         = (const float*)d_in[0];
  const int*   w13       = (const int*)d_in[1];   // int8 values, int32 storage
  const int*   w2        = (const int*)d_in[2];   // int8 values, int32 storage
  const float* w13_scale = (const float*)d_in[3];
  const float* smooth    = (const float*)d_in[4];
  const float* w2_scale  = (const float*)d_in[5];
  // d_in[6] expert_tokens: unused (uniform TPE per expert by construction)

  uint8_t* ws = (uint8_t*)d_ws;
  int8_t* xq = (int8_t*)ws;                        // 16,777,216 B
  int8_t* hq = (int8_t*)ws;                        // 5,767,168 B (overlay: xq dead after gemm1)
  float*  s1 = (float*)(ws + 16777216);            // 16,384 B
  float*  s2 = (float*)(ws + 16777216 + 16384);    // 16,384 B
  float*  y  = (float*)(ws + 16777216 + 32768);    // 46,137,344 B  (total ~63 MB)

  float* out = (float*)d_out;

  quant_x_kernel<<<dim3(T_TOK), dim3(256), 0, stream>>>(x, xq, s1);

  // GEMM1: A=xq (4096,4096), B=w13 (16,2816,4096) -> y (4096,2816)
  gemm_i8_w32_kernel<2 * I_DIM, H_DIM, 44>
      <<<dim3(8 * 2 * 44), dim3(512), 0, stream>>>(
          xq, w13, y, w13_scale, s1);

  act_quant_kernel<<<dim3(T_TOK), dim3(256), 0, stream>>>(y, smooth, hq, s2);

  // GEMM2: A=hq (4096,1408), B=w2 (16,4096,1408) -> out (4096,4096)
  gemm_i8_w32_kernel<H_DIM, I_DIM, 64>
      <<<dim3(8 * 2 * 64), dim3(512), 0, stream>>>(
          hq, w2, out, w2_scale, s2);
}

// Round 9
// 327.647 us; speedup vs baseline: 1.3651x; 1.3651x over previous
//
#include <hip/hip_runtime.h>
#include <stdint.h>

// Problem constants
#define T_TOK 4096
#define H_DIM 4096
#define I_DIM 1408
#define E_NUM 16
#define TPE   256

typedef __attribute__((ext_vector_type(4))) int   i32x4;
typedef __attribute__((ext_vector_type(4))) float f32x4;

// async global->LDS, 16B/lane. LDS dest is WAVE-UNIFORM base; HW writes
// base + lane*16. Global src is per-lane (so we pre-swizzle the source).
__device__ __forceinline__ void gload16(const void* g, void* l) {
  __builtin_amdgcn_global_load_lds(
      (const __attribute__((address_space(1))) void*)g,
      (__attribute__((address_space(3))) void*)l, 16, 0, 0);
}

// ---------------------------------------------------------------------------
// Kernel 1: dynamic per-token quant of x (f32 -> int8 + scale). 1 block/token.
// ---------------------------------------------------------------------------
__global__ __launch_bounds__(256)
void quant_x_kernel(const float* __restrict__ x,
                    int8_t* __restrict__ xq,
                    float* __restrict__ s1) {
  const int t   = blockIdx.x;
  const int tid = threadIdx.x;
  const float* row = x + (size_t)t * H_DIM;

  f32x4 v[4];
  float mx = 0.0f;
#pragma unroll
  for (int i = 0; i < 4; ++i) {
    v[i] = *(const f32x4*)(row + (size_t)(i * 256 + tid) * 4);
#pragma unroll
    for (int j = 0; j < 4; ++j) mx = fmaxf(mx, fabsf(v[i][j]));
  }
#pragma unroll
  for (int off = 32; off > 0; off >>= 1) mx = fmaxf(mx, __shfl_xor(mx, off));
  __shared__ float wmax[4];
  if ((tid & 63) == 0) wmax[tid >> 6] = mx;
  __syncthreads();
  float s = fmaxf(fmaxf(wmax[0], wmax[1]), fmaxf(wmax[2], wmax[3])) / 127.0f;
  s = fmaxf(s, 1e-30f);

  int* orow = (int*)(xq + (size_t)t * H_DIM);
#pragma unroll
  for (int i = 0; i < 4; ++i) {
    int packed = 0;
#pragma unroll
    for (int j = 0; j < 4; ++j) {
      float q = rintf(v[i][j] / s);              // rintf = half-even = jnp.round
      q = fminf(fmaxf(q, -128.0f), 127.0f);
      packed |= ((int)q & 0xff) << (8 * j);
    }
    orow[i * 256 + tid] = packed;
  }
  if (tid == 0) s1[t] = s;
}

// ---------------------------------------------------------------------------
// Kernel 3: h = silu(gate)*up*smooth; per-token quant -> hq, s2. 1 block/token.
// ---------------------------------------------------------------------------
__global__ __launch_bounds__(256)
void act_quant_kernel(const float* __restrict__ y,
                      const float* __restrict__ smooth,
                      int8_t* __restrict__ hq,
                      float* __restrict__ s2) {
  const int t   = blockIdx.x;
  const int e   = t >> 8;               // TPE = 256
  const int tid = threadIdx.x;
  const float* gate = y + (size_t)t * (2 * I_DIM);
  const float* up   = gate + I_DIM;
  const float* ss   = smooth + (size_t)e * I_DIM;
  constexpr int NV = I_DIM / 4;          // 352 vec4 per row

  f32x4 h[2];
  float mx = 0.0f;
#pragma unroll
  for (int i = 0; i < 2; ++i) {
    const int idx = tid + i * 256;
    h[i] = (f32x4)(0.0f);
    if (idx < NV) {
      const f32x4 g4 = *(const f32x4*)(gate + idx * 4);
      const f32x4 u4 = *(const f32x4*)(up + idx * 4);
      const f32x4 s4 = *(const f32x4*)(ss + idx * 4);
#pragma unroll
      for (int j = 0; j < 4; ++j) {
        const float g = g4[j];
        const float sig = 1.0f / (1.0f + expf(-g));
        h[i][j] = ((g * sig) * u4[j]) * s4[j];
        mx = fmaxf(mx, fabsf(h[i][j]));
      }
    }
  }
#pragma unroll
  for (int off = 32; off > 0; off >>= 1) mx = fmaxf(mx, __shfl_xor(mx, off));
  __shared__ float wmax[4];
  if ((tid & 63) == 0) wmax[tid >> 6] = mx;
  __syncthreads();
  float s = fmaxf(fmaxf(wmax[0], wmax[1]), fmaxf(wmax[2], wmax[3])) / 127.0f;
  s = fmaxf(s, 1e-30f);

  int* orow = (int*)(hq + (size_t)t * I_DIM);   // 1408 % 16 == 0, aligned
#pragma unroll
  for (int i = 0; i < 2; ++i) {
    const int idx = tid + i * 256;
    if (idx < NV) {
      int packed = 0;
#pragma unroll
      for (int j = 0; j < 4; ++j) {
        float q = rintf(h[i][j] / s);
        q = fminf(fmaxf(q, -128.0f), 127.0f);
        packed |= ((int)q & 0xff) << (8 * j);
      }
      orow[idx] = packed;
    }
  }
  if (tid == 0) s2[t] = s;
}

// ---------------------------------------------------------------------------
// Grouped int8 GEMM, weights arrive as INT32 (truncated to int8 on the fly).
//   A: (E*TPE, K) int8; B32: (E, N, K) int32; C = ((f32)acc*sN[e,n])*sM[t]
// Tile M=256 (whole expert: weight bytes read ONCE) x N=64, BK=128 (2 MFMA
// k-steps). 512 thr = 8 waves (4M x 2N); wave = 64x32 output.
// BK=128 doubles the per-barrier load burst (A 32KB async + B 32KB int32 regs
// per block) and halves barrier count vs BK=64 -> higher HBM duty cycle at the
// same occupancy (LDS 80KB -> 2 blocks/CU; launch_bounds caps VGPR at 128).
// A: global_load_lds(16B), linear LDS dest + XOR-preswizzled global source.
// B: reg-staged by ALL 512 threads (4x dwordx4 -> byte-pack -> swizzled
//    ds_write_b128). Swizzle (both sides, same involution, 8 blocks/row):
//    LDS(row, blk) = global(row, blk ^ (row&7)).
// ---------------------------------------------------------------------------
template <int N, int K>
__global__ __launch_bounds__(512, 4)
void gemm_i8_w32_kernel(const int8_t* __restrict__ A,
                        const int* __restrict__ B32,
                        float* __restrict__ C,
                        const float* __restrict__ scaleN,
                        const float* __restrict__ scaleM) {
  constexpr int NT = K / 128;
  __shared__ __align__(16) int8_t As[2][256 * 128];  // 32 KB each
  __shared__ __align__(16) int8_t Bs[2][64 * 128];   //  8 KB each

  const int bn   = blockIdx.x;
  const int e    = blockIdx.y;
  const int tid  = threadIdx.x;
  const int lane = tid & 63;
  const int wid  = tid >> 6;          // 0..7
  const int wm   = wid >> 1;          // 0..3  (64-row quadrant of 256)
  const int wn   = wid & 1;           // 0..1  (32-col half of 64)

  const int8_t* Abase = A + (size_t)e * TPE * K;
  const int*    Bbase = B32 + ((size_t)e * N + (size_t)bn * 64) * (size_t)K;

  // --- A staging: 4 chunks/thread; chunk c=i*512+tid -> row=c>>3, blk=c&7 ---
  const int arow = tid >> 3;                    // base row 0..63 (+64*i)
  const int ablk = tid & 7;
  const int akey = arow & 7;                    // (arow+64*i)&7 == akey
  const int agblk = ablk ^ akey;                // pre-swizzled global block
  const int8_t* gA[4];
#pragma unroll
  for (int i = 0; i < 4; ++i)
    gA[i] = Abase + (size_t)(arow + 64 * i) * K + (agblk << 4);

  // --- B staging: 1 chunk/thread; brow=tid>>3 (0..63), bblk=tid&7 ---
  const int brow = tid >> 3;
  const int bblk = tid & 7;
  const int* gB = Bbase + (size_t)brow * K + (bblk << 4);   // int units
  const int bldsOff = brow * 128 + ((bblk ^ (brow & 7)) << 4);

  // --- MFMA fragment LDS read offsets (same XOR on read), 2 k-subtiles ---
  const int r15 = lane & 15;
  const int kg  = lane >> 4;
  int aoff[2][4], boff[2][2];
#pragma unroll
  for (int ks = 0; ks < 2; ++ks) {
#pragma unroll
    for (int m = 0; m < 4; ++m) {
      const int r = wm * 64 + m * 16 + r15;             // 0..255
      aoff[ks][m] = r * 128 + (((ks * 4 + kg) ^ (r & 7)) << 4);
    }
#pragma unroll
    for (int n = 0; n < 2; ++n) {
      const int r = wn * 32 + n * 16 + r15;             // 0..63
      boff[ks][n] = r * 128 + (((ks * 4 + kg) ^ (r & 7)) << 4);
    }
  }

  i32x4 acc[4][2] = {};

  // ---- prologue: stage K-tile 0 into buffer 0 ----
  {
    i32x4 b0 = *(const i32x4*)(gB + 0);
    i32x4 b1 = *(const i32x4*)(gB + 4);
    i32x4 b2 = *(const i32x4*)(gB + 8);
    i32x4 b3 = *(const i32x4*)(gB + 12);
#pragma unroll
    for (int i = 0; i < 4; ++i)
      gload16(gA[i], &As[0][i * 8192 + wid * 1024]);
    i32x4 pk;
    pk[0] = (b0[0] & 255) | ((b0[1] & 255) << 8) | ((b0[2] & 255) << 16) | (b0[3] << 24);
    pk[1] = (b1[0] & 255) | ((b1[1] & 255) << 8) | ((b1[2] & 255) << 16) | (b1[3] << 24);
    pk[2] = (b2[0] & 255) | ((b2[1] & 255) << 8) | ((b2[2] & 255) << 16) | (b2[3] << 24);
    pk[3] = (b3[0] & 255) | ((b3[1] & 255) << 8) | ((b3[2] & 255) << 16) | (b3[3] << 24);
    *(i32x4*)(&Bs[0][bldsOff]) = pk;
  }
  __syncthreads();

  for (int kt = 0; kt < NT; ++kt) {
    const int buf = kt & 1;
    const bool more = (kt + 1) < NT;
    i32x4 n0, n1, n2, n3;
    if (more) {  // issue next-tile loads first: B -> regs, A async->LDS
      const int* g = gB + (kt + 1) * 128;
      n0 = *(const i32x4*)(g + 0);
      n1 = *(const i32x4*)(g + 4);
      n2 = *(const i32x4*)(g + 8);
      n3 = *(const i32x4*)(g + 12);
      const size_t ko = (size_t)(kt + 1) * 128;
#pragma unroll
      for (int i = 0; i < 4; ++i)
        gload16(gA[i] + ko, &As[buf ^ 1][i * 8192 + wid * 1024]);
    }
    // compute on current buffer: 2 k-subtiles x (4m x 2n) MFMAs
#pragma unroll
    for (int ks = 0; ks < 2; ++ks) {
      i32x4 av[4], bv[2];
#pragma unroll
      for (int m = 0; m < 4; ++m) av[m] = *(const i32x4*)(&As[buf][aoff[ks][m]]);
#pragma unroll
      for (int n = 0; n < 2; ++n) bv[n] = *(const i32x4*)(&Bs[buf][boff[ks][n]]);
#pragma unroll
      for (int m = 0; m < 4; ++m)
#pragma unroll
        for (int n = 0; n < 2; ++n)
          acc[m][n] = __builtin_amdgcn_mfma_i32_16x16x64_i8(av[m], bv[n], acc[m][n], 0, 0, 0);
    }
    if (more) {  // pack + swizzled write into next buffer
      i32x4 pk;
      pk[0] = (n0[0] & 255) | ((n0[1] & 255) << 8) | ((n0[2] & 255) << 16) | (n0[3] << 24);
      pk[1] = (n1[0] & 255) | ((n1[1] & 255) << 8) | ((n1[2] & 255) << 16) | (n1[3] << 24);
      pk[2] = (n2[0] & 255) | ((n2[1] & 255) << 8) | ((n2[2] & 255) << 16) | (n2[3] << 24);
      pk[3] = (n3[0] & 255) | ((n3[1] & 255) << 8) | ((n3[2] & 255) << 16) | (n3[3] << 24);
      *(i32x4*)(&Bs[buf ^ 1][bldsOff]) = pk;
    }
    __syncthreads();
  }

  // --- epilogue: C/D layout col = lane&15, row = (lane>>4)*4 + reg ---
  const float* sN = scaleN + (size_t)e * N + (size_t)bn * 64;
  const float* sM = scaleM + e * TPE;
  float* Cbase = C + (size_t)e * TPE * N + (size_t)bn * 64;
#pragma unroll
  for (int m = 0; m < 4; ++m) {
#pragma unroll
    for (int j = 0; j < 4; ++j) {
      const int row = wm * 64 + m * 16 + kg * 4 + j;   // token row 0..255
      const float smv = sM[row];
      float* cr = Cbase + (size_t)row * N;
#pragma unroll
      for (int n = 0; n < 2; ++n) {
        const int col = wn * 32 + n * 16 + r15;
        cr[col] = ((float)acc[m][n][j] * sN[col]) * smv;  // ref mult order
      }
    }
  }
}

// ---------------------------------------------------------------------------
extern "C" void kernel_launch(void* const* d_in, const int* in_sizes, int n_in,
                              void* d_out, int out_size, void* d_ws, size_t ws_size,
                              hipStream_t stream) {
  const float* x         = (const float*)d_in[0];
  const int*   w13       = (const int*)d_in[1];   // int8 values, int32 storage
  const int*   w2        = (const int*)d_in[2];   // int8 values, int32 storage
  const float* w13_scale = (const float*)d_in[3];
  const float* smooth    = (const float*)d_in[4];
  const float* w2_scale  = (const float*)d_in[5];
  // d_in[6] expert_tokens: unused (uniform TPE per expert by construction)

  uint8_t* ws = (uint8_t*)d_ws;
  int8_t* xq = (int8_t*)ws;                        // 16,777,216 B
  int8_t* hq = (int8_t*)ws;                        // 5,767,168 B (overlay: xq dead after gemm1)
  float*  s1 = (float*)(ws + 16777216);            // 16,384 B
  float*  s2 = (float*)(ws + 16777216 + 16384);    // 16,384 B
  float*  y  = (float*)(ws + 16777216 + 32768);    // 46,137,344 B  (total ~63 MB)

  float* out = (float*)d_out;

  quant_x_kernel<<<dim3(T_TOK), dim3(256), 0, stream>>>(x, xq, s1);

  // GEMM1: A=xq (4096,4096), B=w13 (16,2816,4096) -> y (4096,2816)
  gemm_i8_w32_kernel<2 * I_DIM, H_DIM>
      <<<dim3((2 * I_DIM) / 64, E_NUM), dim3(512), 0, stream>>>(
          xq, w13, y, w13_scale, s1);

  act_quant_kernel<<<dim3(T_TOK), dim3(256), 0, stream>>>(y, smooth, hq, s2);

  // GEMM2: A=hq (4096,1408), B=w2 (16,4096,1408) -> out (4096,4096)
  gemm_i8_w32_kernel<H_DIM, I_DIM>
      <<<dim3(H_DIM / 64, E_NUM), dim3(512), 0, stream>>>(
          hq, w2, out, w2_scale, s2);
}

// Round 10
// 323.411 us; speedup vs baseline: 1.3829x; 1.0131x over previous
//
#include <hip/hip_runtime.h>
#include <stdint.h>

// Problem constants
#define T_TOK 4096
#define H_DIM 4096
#define I_DIM 1408
#define E_NUM 16
#define TPE   256

typedef __attribute__((ext_vector_type(4))) int   i32x4;
typedef __attribute__((ext_vector_type(4))) float f32x4;

// async global->LDS, 16B/lane. LDS dest is WAVE-UNIFORM base; HW writes
// base + lane*16. Global src is per-lane (so we pre-swizzle the source).
__device__ __forceinline__ void gload16(const void* g, void* l) {
  __builtin_amdgcn_global_load_lds(
      (const __attribute__((address_space(1))) void*)g,
      (__attribute__((address_space(3))) void*)l, 16, 0, 0);
}

// ---------------------------------------------------------------------------
// Kernel 1: dynamic per-token quant of x (f32 -> int8 + scale). 1 block/token.
// ---------------------------------------------------------------------------
__global__ __launch_bounds__(256)
void quant_x_kernel(const float* __restrict__ x,
                    int8_t* __restrict__ xq,
                    float* __restrict__ s1) {
  const int t   = blockIdx.x;
  const int tid = threadIdx.x;
  const float* row = x + (size_t)t * H_DIM;

  f32x4 v[4];
  float mx = 0.0f;
#pragma unroll
  for (int i = 0; i < 4; ++i) {
    v[i] = *(const f32x4*)(row + (size_t)(i * 256 + tid) * 4);
#pragma unroll
    for (int j = 0; j < 4; ++j) mx = fmaxf(mx, fabsf(v[i][j]));
  }
#pragma unroll
  for (int off = 32; off > 0; off >>= 1) mx = fmaxf(mx, __shfl_xor(mx, off));
  __shared__ float wmax[4];
  if ((tid & 63) == 0) wmax[tid >> 6] = mx;
  __syncthreads();
  float s = fmaxf(fmaxf(wmax[0], wmax[1]), fmaxf(wmax[2], wmax[3])) / 127.0f;
  s = fmaxf(s, 1e-30f);

  int* orow = (int*)(xq + (size_t)t * H_DIM);
#pragma unroll
  for (int i = 0; i < 4; ++i) {
    int packed = 0;
#pragma unroll
    for (int j = 0; j < 4; ++j) {
      float q = rintf(v[i][j] / s);              // rintf = half-even = jnp.round
      q = fminf(fmaxf(q, -128.0f), 127.0f);
      packed |= ((int)q & 0xff) << (8 * j);
    }
    orow[i * 256 + tid] = packed;
  }
  if (tid == 0) s1[t] = s;
}

// ---------------------------------------------------------------------------
// Kernel 3: h = silu(gate)*up*smooth; per-token quant -> hq, s2. 1 block/token.
// ---------------------------------------------------------------------------
__global__ __launch_bounds__(256)
void act_quant_kernel(const float* __restrict__ y,
                      const float* __restrict__ smooth,
                      int8_t* __restrict__ hq,
                      float* __restrict__ s2) {
  const int t   = blockIdx.x;
  const int e   = t >> 8;               // TPE = 256
  const int tid = threadIdx.x;
  const float* gate = y + (size_t)t * (2 * I_DIM);
  const float* up   = gate + I_DIM;
  const float* ss   = smooth + (size_t)e * I_DIM;
  constexpr int NV = I_DIM / 4;          // 352 vec4 per row

  f32x4 h[2];
  float mx = 0.0f;
#pragma unroll
  for (int i = 0; i < 2; ++i) {
    const int idx = tid + i * 256;
    h[i] = (f32x4)(0.0f);
    if (idx < NV) {
      const f32x4 g4 = *(const f32x4*)(gate + idx * 4);
      const f32x4 u4 = *(const f32x4*)(up + idx * 4);
      const f32x4 s4 = *(const f32x4*)(ss + idx * 4);
#pragma unroll
      for (int j = 0; j < 4; ++j) {
        const float g = g4[j];
        const float sig = 1.0f / (1.0f + expf(-g));
        h[i][j] = ((g * sig) * u4[j]) * s4[j];
        mx = fmaxf(mx, fabsf(h[i][j]));
      }
    }
  }
#pragma unroll
  for (int off = 32; off > 0; off >>= 1) mx = fmaxf(mx, __shfl_xor(mx, off));
  __shared__ float wmax[4];
  if ((tid & 63) == 0) wmax[tid >> 6] = mx;
  __syncthreads();
  float s = fmaxf(fmaxf(wmax[0], wmax[1]), fmaxf(wmax[2], wmax[3])) / 127.0f;
  s = fmaxf(s, 1e-30f);

  int* orow = (int*)(hq + (size_t)t * I_DIM);   // 1408 % 16 == 0, aligned
#pragma unroll
  for (int i = 0; i < 2; ++i) {
    const int idx = tid + i * 256;
    if (idx < NV) {
      int packed = 0;
#pragma unroll
      for (int j = 0; j < 4; ++j) {
        float q = rintf(h[i][j] / s);
        q = fminf(fmaxf(q, -128.0f), 127.0f);
        packed |= ((int)q & 0xff) << (8 * j);
      }
      orow[idx] = packed;
    }
  }
  if (tid == 0) s2[t] = s;
}

// ---------------------------------------------------------------------------
// Grouped int8 GEMM, weights arrive as INT32 (truncated to int8 on the fly).
//   A: (E*TPE, K) int8; B32: (E, N, K) int32; C = ((f32)acc*sN[e,n])*sM[t]
// Tile M=256 (whole expert: weight bytes read ONCE) x N=64, BK=128 (2 MFMA
// k-steps). 512 thr = 8 waves (4M x 2N); wave = 64x32 output.
// XCD-pinned expert mapping (T1): HW assigns blockIdx round-robin to XCDs,
// so rid&7 = XCD. Each XCD owns exactly 2 experts -> its A working set is
// 2 MB (fits 4 MB L2) and every co-resident block re-touches the same A
// bytes each K-iter, keeping them LRU-hot against the B stream. Without
// this, all 16 experts' A tiles (16 MB) thrash every XCD's L2 and A is
// re-fetched from HBM (~+700 MB on gemm1).
// A: global_load_lds(16B), linear LDS dest + XOR-preswizzled global source.
// B: reg-staged by ALL 512 threads (4x dwordx4 -> byte-pack -> swizzled
//    ds_write_b128). Swizzle (both sides, same involution, 8 blocks/row):
//    LDS(row, blk) = global(row, blk ^ (row&7)).
// ---------------------------------------------------------------------------
template <int N, int K, int NBLK>   // NBLK = N/64
__global__ __launch_bounds__(512, 4)
void gemm_i8_w32_kernel(const int8_t* __restrict__ A,
                        const int* __restrict__ B32,
                        float* __restrict__ C,
                        const float* __restrict__ scaleN,
                        const float* __restrict__ scaleM) {
  constexpr int NT = K / 128;
  __shared__ __align__(16) int8_t As[2][256 * 128];  // 32 KB each
  __shared__ __align__(16) int8_t Bs[2][64 * 128];   //  8 KB each

  // --- XCD-pinned (expert, n-tile) mapping ---
  const int rid  = blockIdx.x;
  const int xcd  = rid & 7;                  // HW round-robin XCD id
  const int slot = rid >> 3;                 // 0 .. 2*NBLK-1, in-order per XCD
  const int el   = (slot >= NBLK) ? 1 : 0;
  const int e    = 2 * xcd + el;             // 2 experts per XCD
  const int bn   = slot - el * NBLK;

  const int tid  = threadIdx.x;
  const int lane = tid & 63;
  const int wid  = tid >> 6;          // 0..7
  const int wm   = wid >> 1;          // 0..3  (64-row quadrant of 256)
  const int wn   = wid & 1;           // 0..1  (32-col half of 64)

  const int8_t* Abase = A + (size_t)e * TPE * K;
  const int*    Bbase = B32 + ((size_t)e * N + (size_t)bn * 64) * (size_t)K;

  // --- A staging: 4 chunks/thread; chunk c=i*512+tid -> row=c>>3, blk=c&7 ---
  const int arow = tid >> 3;                    // base row 0..63 (+64*i)
  const int ablk = tid & 7;
  const int akey = arow & 7;                    // (arow+64*i)&7 == akey
  const int agblk = ablk ^ akey;                // pre-swizzled global block
  const int8_t* gA[4];
#pragma unroll
  for (int i = 0; i < 4; ++i)
    gA[i] = Abase + (size_t)(arow + 64 * i) * K + (agblk << 4);

  // --- B staging: 1 chunk/thread; brow=tid>>3 (0..63), bblk=tid&7 ---
  const int brow = tid >> 3;
  const int bblk = tid & 7;
  const int* gB = Bbase + (size_t)brow * K + (bblk << 4);   // int units
  const int bldsOff = brow * 128 + ((bblk ^ (brow & 7)) << 4);

  // --- MFMA fragment LDS read offsets (same XOR on read), 2 k-subtiles ---
  const int r15 = lane & 15;
  const int kg  = lane >> 4;
  int aoff[2][4], boff[2][2];
#pragma unroll
  for (int ks = 0; ks < 2; ++ks) {
#pragma unroll
    for (int m = 0; m < 4; ++m) {
      const int r = wm * 64 + m * 16 + r15;             // 0..255
      aoff[ks][m] = r * 128 + (((ks * 4 + kg) ^ (r & 7)) << 4);
    }
#pragma unroll
    for (int n = 0; n < 2; ++n) {
      const int r = wn * 32 + n * 16 + r15;             // 0..63
      boff[ks][n] = r * 128 + (((ks * 4 + kg) ^ (r & 7)) << 4);
    }
  }

  i32x4 acc[4][2] = {};

  // ---- prologue: stage K-tile 0 into buffer 0 ----
  {
    i32x4 b0 = *(const i32x4*)(gB + 0);
    i32x4 b1 = *(const i32x4*)(gB + 4);
    i32x4 b2 = *(const i32x4*)(gB + 8);
    i32x4 b3 = *(const i32x4*)(gB + 12);
#pragma unroll
    for (int i = 0; i < 4; ++i)
      gload16(gA[i], &As[0][i * 8192 + wid * 1024]);
    i32x4 pk;
    pk[0] = (b0[0] & 255) | ((b0[1] & 255) << 8) | ((b0[2] & 255) << 16) | (b0[3] << 24);
    pk[1] = (b1[0] & 255) | ((b1[1] & 255) << 8) | ((b1[2] & 255) << 16) | (b1[3] << 24);
    pk[2] = (b2[0] & 255) | ((b2[1] & 255) << 8) | ((b2[2] & 255) << 16) | (b2[3] << 24);
    pk[3] = (b3[0] & 255) | ((b3[1] & 255) << 8) | ((b3[2] & 255) << 16) | (b3[3] << 24);
    *(i32x4*)(&Bs[0][bldsOff]) = pk;
  }
  __syncthreads();

  for (int kt = 0; kt < NT; ++kt) {
    const int buf = kt & 1;
    const bool more = (kt + 1) < NT;
    i32x4 n0, n1, n2, n3;
    if (more) {  // issue next-tile loads first: B -> regs, A async->LDS
      const int* g = gB + (kt + 1) * 128;
      n0 = *(const i32x4*)(g + 0);
      n1 = *(const i32x4*)(g + 4);
      n2 = *(const i32x4*)(g + 8);
      n3 = *(const i32x4*)(g + 12);
      const size_t ko = (size_t)(kt + 1) * 128;
#pragma unroll
      for (int i = 0; i < 4; ++i)
        gload16(gA[i] + ko, &As[buf ^ 1][i * 8192 + wid * 1024]);
    }
    // compute on current buffer: 2 k-subtiles x (4m x 2n) MFMAs
#pragma unroll
    for (int ks = 0; ks < 2; ++ks) {
      i32x4 av[4], bv[2];
#pragma unroll
      for (int m = 0; m < 4; ++m) av[m] = *(const i32x4*)(&As[buf][aoff[ks][m]]);
#pragma unroll
      for (int n = 0; n < 2; ++n) bv[n] = *(const i32x4*)(&Bs[buf][boff[ks][n]]);
#pragma unroll
      for (int m = 0; m < 4; ++m)
#pragma unroll
        for (int n = 0; n < 2; ++n)
          acc[m][n] = __builtin_amdgcn_mfma_i32_16x16x64_i8(av[m], bv[n], acc[m][n], 0, 0, 0);
    }
    if (more) {  // pack + swizzled write into next buffer
      i32x4 pk;
      pk[0] = (n0[0] & 255) | ((n0[1] & 255) << 8) | ((n0[2] & 255) << 16) | (n0[3] << 24);
      pk[1] = (n1[0] & 255) | ((n1[1] & 255) << 8) | ((n1[2] & 255) << 16) | (n1[3] << 24);
      pk[2] = (n2[0] & 255) | ((n2[1] & 255) << 8) | ((n2[2] & 255) << 16) | (n2[3] << 24);
      pk[3] = (n3[0] & 255) | ((n3[1] & 255) << 8) | ((n3[2] & 255) << 16) | (n3[3] << 24);
      *(i32x4*)(&Bs[buf ^ 1][bldsOff]) = pk;
    }
    __syncthreads();
  }

  // --- epilogue: C/D layout col = lane&15, row = (lane>>4)*4 + reg ---
  const float* sN = scaleN + (size_t)e * N + (size_t)bn * 64;
  const float* sM = scaleM + e * TPE;
  float* Cbase = C + (size_t)e * TPE * N + (size_t)bn * 64;
#pragma unroll
  for (int m = 0; m < 4; ++m) {
#pragma unroll
    for (int j = 0; j < 4; ++j) {
      const int row = wm * 64 + m * 16 + kg * 4 + j;   // token row 0..255
      const float smv = sM[row];
      float* cr = Cbase + (size_t)row * N;
#pragma unroll
      for (int n = 0; n < 2; ++n) {
        const int col = wn * 32 + n * 16 + r15;
        cr[col] = ((float)acc[m][n][j] * sN[col]) * smv;  // ref mult order
      }
    }
  }
}

// ---------------------------------------------------------------------------
extern "C" void kernel_launch(void* const* d_in, const int* in_sizes, int n_in,
                              void* d_out, int out_size, void* d_ws, size_t ws_size,
                              hipStream_t stream) {
  const float* x         = (const float*)d_in[0];
  const int*   w13       = (const int*)d_in[1];   // int8 values, int32 storage
  const int*   w2        = (const int*)d_in[2];   // int8 values, int32 storage
  const float* w13_scale = (const float*)d_in[3];
  const float* smooth    = (const float*)d_in[4];
  const float* w2_scale  = (const float*)d_in[5];
  // d_in[6] expert_tokens: unused (uniform TPE per expert by construction)

  uint8_t* ws = (uint8_t*)d_ws;
  int8_t* xq = (int8_t*)ws;                        // 16,777,216 B
  int8_t* hq = (int8_t*)ws;                        // 5,767,168 B (overlay: xq dead after gemm1)
  float*  s1 = (float*)(ws + 16777216);            // 16,384 B
  float*  s2 = (float*)(ws + 16777216 + 16384);    // 16,384 B
  float*  y  = (float*)(ws + 16777216 + 32768);    // 46,137,344 B  (total ~63 MB)

  float* out = (float*)d_out;

  quant_x_kernel<<<dim3(T_TOK), dim3(256), 0, stream>>>(x, xq, s1);

  // GEMM1: A=xq (4096,4096), B=w13 (16,2816,4096) -> y (4096,2816)
  gemm_i8_w32_kernel<2 * I_DIM, H_DIM, 44>
      <<<dim3(8 * 2 * 44), dim3(512), 0, stream>>>(
          xq, w13, y, w13_scale, s1);

  act_quant_kernel<<<dim3(T_TOK), dim3(256), 0, stream>>>(y, smooth, hq, s2);

  // GEMM2: A=hq (4096,1408), B=w2 (16,4096,1408) -> out (4096,4096)
  gemm_i8_w32_kernel<H_DIM, I_DIM, 64>
      <<<dim3(8 * 2 * 64), dim3(512), 0, stream>>>(
          hq, w2, out, w2_scale, s2);
}

// Round 11
// 282.830 us; speedup vs baseline: 1.5814x; 1.1435x over previous
//
#include <hip/hip_runtime.h>
#include <stdint.h>

// Problem constants
#define T_TOK 4096
#define H_DIM 4096
#define I_DIM 1408
#define E_NUM 16
#define TPE   256

typedef __attribute__((ext_vector_type(4))) int   i32x4;
typedef __attribute__((ext_vector_type(4))) float f32x4;

// counted waits (T4): vmcnt never drains to 0 in the steady-state loop.
#define VMCNT(n) asm volatile("s_waitcnt vmcnt(" #n ")" ::: "memory")
#define LGKM0()  asm volatile("s_waitcnt lgkmcnt(0)" ::: "memory")

// async global->LDS, 16B/lane. LDS dest is WAVE-UNIFORM base; HW writes
// base + lane*16. Global src is per-lane (so we pre-swizzle the source).
__device__ __forceinline__ void gload16(const void* g, void* l) {
  __builtin_amdgcn_global_load_lds(
      (const __attribute__((address_space(1))) void*)g,
      (__attribute__((address_space(3))) void*)l, 16, 0, 0);
}

// ---------------------------------------------------------------------------
// Kernel 1: dynamic per-token quant of x (f32 -> int8 + scale). 1 block/token.
// ---------------------------------------------------------------------------
__global__ __launch_bounds__(256)
void quant_x_kernel(const float* __restrict__ x,
                    int8_t* __restrict__ xq,
                    float* __restrict__ s1) {
  const int t   = blockIdx.x;
  const int tid = threadIdx.x;
  const float* row = x + (size_t)t * H_DIM;

  f32x4 v[4];
  float mx = 0.0f;
#pragma unroll
  for (int i = 0; i < 4; ++i) {
    v[i] = *(const f32x4*)(row + (size_t)(i * 256 + tid) * 4);
#pragma unroll
    for (int j = 0; j < 4; ++j) mx = fmaxf(mx, fabsf(v[i][j]));
  }
#pragma unroll
  for (int off = 32; off > 0; off >>= 1) mx = fmaxf(mx, __shfl_xor(mx, off));
  __shared__ float wmax[4];
  if ((tid & 63) == 0) wmax[tid >> 6] = mx;
  __syncthreads();
  float s = fmaxf(fmaxf(wmax[0], wmax[1]), fmaxf(wmax[2], wmax[3])) / 127.0f;
  s = fmaxf(s, 1e-30f);

  int* orow = (int*)(xq + (size_t)t * H_DIM);
#pragma unroll
  for (int i = 0; i < 4; ++i) {
    int packed = 0;
#pragma unroll
    for (int j = 0; j < 4; ++j) {
      float q = rintf(v[i][j] / s);              // rintf = half-even = jnp.round
      q = fminf(fmaxf(q, -128.0f), 127.0f);
      packed |= ((int)q & 0xff) << (8 * j);
    }
    orow[i * 256 + tid] = packed;
  }
  if (tid == 0) s1[t] = s;
}

// ---------------------------------------------------------------------------
// Kernel 3: h = silu(gate)*up*smooth; per-token quant -> hq, s2. 1 block/token.
// ---------------------------------------------------------------------------
__global__ __launch_bounds__(256)
void act_quant_kernel(const float* __restrict__ y,
                      const float* __restrict__ smooth,
                      int8_t* __restrict__ hq,
                      float* __restrict__ s2) {
  const int t   = blockIdx.x;
  const int e   = t >> 8;               // TPE = 256
  const int tid = threadIdx.x;
  const float* gate = y + (size_t)t * (2 * I_DIM);
  const float* up   = gate + I_DIM;
  const float* ss   = smooth + (size_t)e * I_DIM;
  constexpr int NV = I_DIM / 4;          // 352 vec4 per row

  f32x4 h[2];
  float mx = 0.0f;
#pragma unroll
  for (int i = 0; i < 2; ++i) {
    const int idx = tid + i * 256;
    h[i] = (f32x4)(0.0f);
    if (idx < NV) {
      const f32x4 g4 = *(const f32x4*)(gate + idx * 4);
      const f32x4 u4 = *(const f32x4*)(up + idx * 4);
      const f32x4 s4 = *(const f32x4*)(ss + idx * 4);
#pragma unroll
      for (int j = 0; j < 4; ++j) {
        const float g = g4[j];
        const float sig = 1.0f / (1.0f + expf(-g));
        h[i][j] = ((g * sig) * u4[j]) * s4[j];
        mx = fmaxf(mx, fabsf(h[i][j]));
      }
    }
  }
#pragma unroll
  for (int off = 32; off > 0; off >>= 1) mx = fmaxf(mx, __shfl_xor(mx, off));
  __shared__ float wmax[4];
  if ((tid & 63) == 0) wmax[tid >> 6] = mx;
  __syncthreads();
  float s = fmaxf(fmaxf(wmax[0], wmax[1]), fmaxf(wmax[2], wmax[3])) / 127.0f;
  s = fmaxf(s, 1e-30f);

  int* orow = (int*)(hq + (size_t)t * I_DIM);   // 1408 % 16 == 0, aligned
#pragma unroll
  for (int i = 0; i < 2; ++i) {
    const int idx = tid + i * 256;
    if (idx < NV) {
      int packed = 0;
#pragma unroll
      for (int j = 0; j < 4; ++j) {
        float q = rintf(h[i][j] / s);
        q = fminf(fmaxf(q, -128.0f), 127.0f);
        packed |= ((int)q & 0xff) << (8 * j);
      }
      orow[idx] = packed;
    }
  }
  if (tid == 0) s2[t] = s;
}

// ---------------------------------------------------------------------------
// Grouped int8 GEMM, weights arrive as INT32 (truncated to int8 on the fly).
//   A: (E*TPE, K) int8; B32: (E, N, K) int32; C = ((f32)acc*sN[e,n])*sM[t]
// Tile M=256 (whole expert) x N=64, BK=128. 512 thr = 8 waves (4M x 2N).
//
// Counted-vmcnt schedule (T4) — one s_barrier/iter, vmcnt floor = 4:
//   iter t (entering: As[t&1],Bs[t&1] valid; outstanding = B(t+1) regs x4):
//     1. issue A(t+1) -> As[(t+1)&1]          (outstanding: B(t+1)4 + A(t+1)4)
//     2. ds_read + 16 MFMA on tile t
//     3. VMCNT(4)  -> B(t+1) regs arrived (A(t+1) still in flight)
//     4. pack B(t+1) -> ds_write Bs[(t+1)&1]
//     5. issue B(t+2) -> regs                 (outstanding: A(t+1)4 + B(t+2)4)
//     6. VMCNT(4)  -> A(t+1) done; B(t+2) stays in flight ACROSS the barrier
//     7. LGKM0 (ds_write visible) + s_barrier
//   Issue order is pinned by asm "memory" clobbers; wait counts follow from it.
//   Buffer safety: As/Bs[(t+1)&1] were last READ in iter t-1; the iter-t-1
//   barrier guarantees those reads completed before step 1/4 overwrite them.
// XCD-pinned expert mapping (kept from R10, free): rid&7 = XCD owns 2 experts.
// Swizzle (both sides, same involution): LDS(row,blk)=global(row,blk^(row&7)).
// ---------------------------------------------------------------------------
template <int N, int K, int NBLK>   // NBLK = N/64
__global__ __launch_bounds__(512, 4)
void gemm_i8_w32_kernel(const int8_t* __restrict__ A,
                        const int* __restrict__ B32,
                        float* __restrict__ C,
                        const float* __restrict__ scaleN,
                        const float* __restrict__ scaleM) {
  constexpr int NT = K / 128;
  __shared__ __align__(16) int8_t As[2][256 * 128];  // 32 KB each
  __shared__ __align__(16) int8_t Bs[2][64 * 128];   //  8 KB each

  // --- XCD-pinned (expert, n-tile) mapping ---
  const int rid  = blockIdx.x;
  const int xcd  = rid & 7;                  // HW round-robin XCD id
  const int slot = rid >> 3;                 // 0 .. 2*NBLK-1
  const int el   = (slot >= NBLK) ? 1 : 0;
  const int e    = 2 * xcd + el;             // 2 experts per XCD
  const int bn   = slot - el * NBLK;

  const int tid  = threadIdx.x;
  const int lane = tid & 63;
  const int wid  = tid >> 6;          // 0..7
  const int wm   = wid >> 1;          // 0..3  (64-row quadrant of 256)
  const int wn   = wid & 1;           // 0..1  (32-col half of 64)

  const int8_t* Abase = A + (size_t)e * TPE * K;
  const int*    Bbase = B32 + ((size_t)e * N + (size_t)bn * 64) * (size_t)K;

  // --- A staging: 4 chunks/thread; chunk c=i*512+tid -> row=c>>3, blk=c&7 ---
  const int arow = tid >> 3;                    // base row 0..63 (+64*i)
  const int ablk = tid & 7;
  const int akey = arow & 7;                    // (arow+64*i)&7 == akey
  const int agblk = ablk ^ akey;                // pre-swizzled global block
  const int8_t* gA[4];
#pragma unroll
  for (int i = 0; i < 4; ++i)
    gA[i] = Abase + (size_t)(arow + 64 * i) * K + (agblk << 4);

  // --- B staging: 1 chunk/thread; brow=tid>>3 (0..63), bblk=tid&7 ---
  const int brow = tid >> 3;
  const int bblk = tid & 7;
  const int* gB = Bbase + (size_t)brow * K + (bblk << 4);   // int units
  const int bldsOff = brow * 128 + ((bblk ^ (brow & 7)) << 4);

  // --- MFMA fragment LDS read offsets (same XOR on read), 2 k-subtiles ---
  const int r15 = lane & 15;
  const int kg  = lane >> 4;
  int aoff[2][4], boff[2][2];
#pragma unroll
  for (int ks = 0; ks < 2; ++ks) {
#pragma unroll
    for (int m = 0; m < 4; ++m) {
      const int r = wm * 64 + m * 16 + r15;             // 0..255
      aoff[ks][m] = r * 128 + (((ks * 4 + kg) ^ (r & 7)) << 4);
    }
#pragma unroll
    for (int n = 0; n < 2; ++n) {
      const int r = wn * 32 + n * 16 + r15;             // 0..63
      boff[ks][n] = r * 128 + (((ks * 4 + kg) ^ (r & 7)) << 4);
    }
  }

  i32x4 acc[4][2] = {};
  i32x4 n0, n1, n2, n3;     // B(t+1) register stage, live across the barrier

  // ---- prologue ----
  {
    // B(0) -> regs, A(0) -> As[0]
    i32x4 b0 = *(const i32x4*)(gB + 0);
    i32x4 b1 = *(const i32x4*)(gB + 4);
    i32x4 b2 = *(const i32x4*)(gB + 8);
    i32x4 b3 = *(const i32x4*)(gB + 12);
#pragma unroll
    for (int i = 0; i < 4; ++i)
      gload16(gA[i], &As[0][i * 8192 + wid * 1024]);
    VMCNT(4);                       // B(0) arrived; A(0) in flight
    i32x4 pk;
    pk[0] = (b0[0] & 255) | ((b0[1] & 255) << 8) | ((b0[2] & 255) << 16) | (b0[3] << 24);
    pk[1] = (b1[0] & 255) | ((b1[1] & 255) << 8) | ((b1[2] & 255) << 16) | (b1[3] << 24);
    pk[2] = (b2[0] & 255) | ((b2[1] & 255) << 8) | ((b2[2] & 255) << 16) | (b2[3] << 24);
    pk[3] = (b3[0] & 255) | ((b3[1] & 255) << 8) | ((b3[2] & 255) << 16) | (b3[3] << 24);
    *(i32x4*)(&Bs[0][bldsOff]) = pk;
    if (NT > 1) {                   // issue B(1)
      const int* g = gB + 128;
      n0 = *(const i32x4*)(g + 0);
      n1 = *(const i32x4*)(g + 4);
      n2 = *(const i32x4*)(g + 8);
      n3 = *(const i32x4*)(g + 12);
      VMCNT(4);                     // A(0) done; B(1) stays in flight
    } else {
      VMCNT(0);
    }
    LGKM0();
    __builtin_amdgcn_s_barrier();
  }

  for (int t = 0; t < NT; ++t) {
    const int cur = t & 1;
    // 1. issue A(t+1) async -> other buffer (read of it finished last iter)
    if (t + 1 < NT) {
      const size_t ko = (size_t)(t + 1) * 128;
#pragma unroll
      for (int i = 0; i < 4; ++i)
        gload16(gA[i] + ko, &As[cur ^ 1][i * 8192 + wid * 1024]);
    }
    // 2. compute tile t: 2 k-subtiles x (4m x 2n) MFMAs
#pragma unroll
    for (int ks = 0; ks < 2; ++ks) {
      i32x4 av[4], bv[2];
#pragma unroll
      for (int m = 0; m < 4; ++m) av[m] = *(const i32x4*)(&As[cur][aoff[ks][m]]);
#pragma unroll
      for (int n = 0; n < 2; ++n) bv[n] = *(const i32x4*)(&Bs[cur][boff[ks][n]]);
#pragma unroll
      for (int m = 0; m < 4; ++m)
#pragma unroll
        for (int n = 0; n < 2; ++n)
          acc[m][n] = __builtin_amdgcn_mfma_i32_16x16x64_i8(av[m], bv[n], acc[m][n], 0, 0, 0);
    }
    if (t + 1 < NT) {
      // 3. B(t+1) regs ready (A(t+1) still in flight)
      VMCNT(4);
      // 4. pack + swizzled ds_write into Bs[(t+1)&1]
      i32x4 pk;
      pk[0] = (n0[0] & 255) | ((n0[1] & 255) << 8) | ((n0[2] & 255) << 16) | (n0[3] << 24);
      pk[1] = (n1[0] & 255) | ((n1[1] & 255) << 8) | ((n1[2] & 255) << 16) | (n1[3] << 24);
      pk[2] = (n2[0] & 255) | ((n2[1] & 255) << 8) | ((n2[2] & 255) << 16) | (n2[3] << 24);
      pk[3] = (n3[0] & 255) | ((n3[1] & 255) << 8) | ((n3[2] & 255) << 16) | (n3[3] << 24);
      *(i32x4*)(&Bs[cur ^ 1][bldsOff]) = pk;
      // 5. issue B(t+2); 6. drain A(t+1) but keep B(t+2) in flight
      if (t + 2 < NT) {
        const int* g = gB + (t + 2) * 128;
        n0 = *(const i32x4*)(g + 0);
        n1 = *(const i32x4*)(g + 4);
        n2 = *(const i32x4*)(g + 8);
        n3 = *(const i32x4*)(g + 12);
        VMCNT(4);
      } else {
        VMCNT(0);                   // one full drain, last-but-one iter only
      }
      // 7. ds_write visible to all, then barrier
      LGKM0();
      __builtin_amdgcn_s_barrier();
    }
  }

  // --- epilogue: C/D layout col = lane&15, row = (lane>>4)*4 + reg ---
  const float* sN = scaleN + (size_t)e * N + (size_t)bn * 64;
  const float* sM = scaleM + e * TPE;
  float* Cbase = C + (size_t)e * TPE * N + (size_t)bn * 64;
#pragma unroll
  for (int m = 0; m < 4; ++m) {
#pragma unroll
    for (int j = 0; j < 4; ++j) {
      const int row = wm * 64 + m * 16 + kg * 4 + j;   // token row 0..255
      const float smv = sM[row];
      float* cr = Cbase + (size_t)row * N;
#pragma unroll
      for (int n = 0; n < 2; ++n) {
        const int col = wn * 32 + n * 16 + r15;
        cr[col] = ((float)acc[m][n][j] * sN[col]) * smv;  // ref mult order
      }
    }
  }
}

// ---------------------------------------------------------------------------
extern "C" void kernel_launch(void* const* d_in, const int* in_sizes, int n_in,
                              void* d_out, int out_size, void* d_ws, size_t ws_size,
                              hipStream_t stream) {
  const float* x         = (const float*)d_in[0];
  const int*   w13       = (const int*)d_in[1];   // int8 values, int32 storage
  const int*   w2        = (const int*)d_in[2];   // int8 values, int32 storage
  const float* w13_scale = (const float*)d_in[3];
  const float* smooth    = (const float*)d_in[4];
  const float* w2_scale  = (const float*)d_in[5];
  // d_in[6] expert_tokens: unused (uniform TPE per expert by construction)

  uint8_t* ws = (uint8_t*)d_ws;
  int8_t* xq = (int8_t*)ws;                        // 16,777,216 B
  int8_t* hq = (int8_t*)ws;                        // 5,767,168 B (overlay: xq dead after gemm1)
  float*  s1 = (float*)(ws + 16777216);            // 16,384 B
  float*  s2 = (float*)(ws + 16777216 + 16384);    // 16,384 B
  float*  y  = (float*)(ws + 16777216 + 32768);    // 46,137,344 B  (total ~63 MB)

  float* out = (float*)d_out;

  quant_x_kernel<<<dim3(T_TOK), dim3(256), 0, stream>>>(x, xq, s1);

  // GEMM1: A=xq (4096,4096), B=w13 (16,2816,4096) -> y (4096,2816)
  gemm_i8_w32_kernel<2 * I_DIM, H_DIM, 44>
      <<<dim3(8 * 2 * 44), dim3(512), 0, stream>>>(
          xq, w13, y, w13_scale, s1);

  act_quant_kernel<<<dim3(T_TOK), dim3(256), 0, stream>>>(y, smooth, hq, s2);

  // GEMM2: A=hq (4096,1408), B=w2 (16,4096,1408) -> out (4096,4096)
  gemm_i8_w32_kernel<H_DIM, I_DIM, 64>
      <<<dim3(8 * 2 * 64), dim3(512), 0, stream>>>(
          hq, w2, out, w2_scale, s2);
}